// Round 5
// baseline (1277.020 us; speedup 1.0000x reference)
//
#include <hip/hip_runtime.h>

#define NB 4
#define NH 1024
#define NW 1024
#define NHW (NH * NW)

#define TS 64          // source tile side
#define HP 16          // halo
#define RS 96          // region side = TS + 2*HP
#define REG_PX (RS * RS)

__device__ __forceinline__ float srgb2lin(float v) {
    return v > 0.04045f ? powf((v + 0.055f) * (1.0f / 1.055f), 2.4f) : v * (1.0f / 12.92f);
}

__device__ __forceinline__ float labf(float t) {
    return t > 0.008856f ? cbrtf(t) : 7.787f * t + 4.0f / 29.0f;
}

// Compute Lab for both images, INTERLEAVED (hw,3) output for gather locality.
__global__ void lab_kernel(const float* __restrict__ I0, const float* __restrict__ I1,
                           float* __restrict__ lab0, float* __restrict__ lab1) {
    int idx = blockIdx.x * blockDim.x + threadIdx.x;
    const int total = 2 * NB * NHW;
    if (idx >= total) return;
    int img = (idx >= NB * NHW) ? 1 : 0;
    int p = idx - img * NB * NHW;
    int b = p / NHW;
    int hw = p - b * NHW;
    const float* src = (img ? I1 : I0) + (size_t)b * 3 * NHW + hw;
    float* dst = (img ? lab1 : lab0) + ((size_t)b * NHW + hw) * 3;

    float r = srgb2lin(src[0]);
    float g = srgb2lin(src[NHW]);
    float bl = srgb2lin(src[2 * NHW]);

    float X = (0.412453f * r + 0.35758f * g + 0.180423f * bl) * (1.0f / 0.95047f);
    float Y = (0.212671f * r + 0.71516f * g + 0.072169f * bl);
    float Z = (0.019334f * r + 0.119193f * g + 0.950227f * bl) * (1.0f / 1.08883f);

    float fx = labf(X);
    float fy = labf(Y);
    float fz = labf(Z);

    dst[0] = 116.0f * fy - 16.0f;
    dst[1] = 500.0f * (fx - fy);
    dst[2] = 200.0f * (fy - fz);
}

// Fused z-metric + forward splat, LDS-privatized per 64x64 source tile.
// 1024 threads, 4 px/thread; 147 KB LDS region => 1 block/CU, 16 waves/CU.
// Region coverage factor (96/64)^2 = 2.25 (vs 4 for 32/64) => ~half the
// atomic RMW writeback traffic, which is the measured ~1.1 TB/s ceiling.
// acc3: interleaved (b, hw, 3) color accum; wacc: planar (b, hw) weight accum.
__global__ __launch_bounds__(1024, 4) void splat_tile_kernel(
        const float* __restrict__ img,
        const float* __restrict__ lab_a,   // interleaved 3
        const float* __restrict__ lab_b,   // interleaved 3
        const float* __restrict__ flow,
        float* __restrict__ acc3,
        float* __restrict__ wacc) {
    __shared__ float reg[REG_PX * 4];   // 147456 B

    const int t = threadIdx.x;
    const int b = blockIdx.z;
    const int tile_x0 = blockIdx.x * TS;
    const int tile_y0 = blockIdx.y * TS;
    const int ox = tile_x0 - HP;
    const int oy = tile_y0 - HP;

    {
        float4* r4 = (float4*)reg;
        const float4 z4 = make_float4(0.f, 0.f, 0.f, 0.f);
        for (int i = t; i < REG_PX; i += 1024) r4[i] = z4;
    }
    __syncthreads();

    const int tx = t & 63;
    const int ty0 = t >> 6;   // 0..15

    const float* fb = flow  + (size_t)b * 2 * NHW;
    const float* ib = img   + (size_t)b * 3 * NHW;
    const float* la = lab_a + (size_t)b * NHW * 3;
    const float* lb = lab_b + (size_t)b * NHW * 3;
    float* a3 = acc3 + (size_t)b * NHW * 3;
    float* wv = wacc + (size_t)b * NHW;

#pragma unroll
    for (int kk = 0; kk < 4; ++kk) {
        const int y = tile_y0 + ty0 + kk * 16;
        const int x = tile_x0 + tx;
        const int hw = y * NW + x;

        const float fy_d = fb[hw];         // flow channel 0 = y displacement
        const float fx_d = fb[NHW + hw];   // flow channel 1 = x displacement

        // ---- backward warp gather (grid_sample_border convention) ----
        float base_y = -1.0f + 2.0f * (float)y / (float)(NH - 1);
        float base_x = -1.0f + 2.0f * (float)x / (float)(NW - 1);
        float gy = 2.0f * fy_d / (float)NH + base_y;
        float gx = 2.0f * fx_d / (float)NW + base_x;
        float ys = fminf(fmaxf(((gy + 1.0f) * (float)NH - 1.0f) * 0.5f, 0.0f), (float)(NH - 1));
        float xs = fminf(fmaxf(((gx + 1.0f) * (float)NW - 1.0f) * 0.5f, 0.0f), (float)(NW - 1));
        float y0f = floorf(ys), x0f = floorf(xs);
        int y0 = (int)y0f, x0 = (int)x0f;
        int y1 = min(y0 + 1, NH - 1), x1 = min(x0 + 1, NW - 1);
        float wy = ys - y0f, wx = xs - x0f;

        const float* p00 = lb + (size_t)(y0 * NW + x0) * 3;
        const float* p01 = lb + (size_t)(y0 * NW + x1) * 3;
        const float* p10 = lb + (size_t)(y1 * NW + x0) * 3;
        const float* p11 = lb + (size_t)(y1 * NW + x1) * 3;
        const float* pa  = la + (size_t)hw * 3;

        float ss = 0.0f;
#pragma unroll
        for (int c = 0; c < 3; ++c) {
            float top = p00[c] * (1.0f - wx) + p01[c] * wx;
            float bot = p10[c] * (1.0f - wx) + p11[c] * wx;
            float v = top * (1.0f - wy) + bot * wy;
            float d = pa[c] - v;
            ss += d * d;
        }
        float w = expf(-0.1f * sqrtf(ss));

        // ---- forward splat ----
        float sx = fx_d + (float)x;
        float sy = fy_d + (float)y;
        int ix0 = (int)floorf(sx);
        int iy0 = (int)floorf(sy);

        float c0 = ib[hw] * w;
        float c1 = ib[NHW + hw] * w;
        float c2 = ib[2 * NHW + hw] * w;

#pragma unroll
        for (int dy = 0; dy < 2; ++dy) {
            int yi = iy0 + dy;
            if (yi < 0 || yi >= NH) continue;
            float wgy = 1.0f - fabsf(sy - (float)yi);
#pragma unroll
            for (int dx = 0; dx < 2; ++dx) {
                int xi = ix0 + dx;
                if (xi < 0 || xi >= NW) continue;
                float wg = wgy * (1.0f - fabsf(sx - (float)xi));
                int rx = xi - ox;
                int ry = yi - oy;
                if (rx >= 0 && rx < RS && ry >= 0 && ry < RS) {
                    float* p = reg + (ry * RS + rx) * 4;
                    atomicAdd(p + 0, c0 * wg);
                    atomicAdd(p + 1, c1 * wg);
                    atomicAdd(p + 2, c2 * wg);
                    atomicAdd(p + 3, w * wg);
                } else {
                    int o = yi * NW + xi;
                    float* p = a3 + (size_t)o * 3;
                    atomicAdd(p + 0, c0 * wg);
                    atomicAdd(p + 1, c1 * wg);
                    atomicAdd(p + 2, c2 * wg);
                    atomicAdd(wv + o, w * wg);
                }
            }
        }
    }
    __syncthreads();

    // ---- flush LDS region to global (coalesced, aggregated, zero-skipped) ----
    for (int i = t; i < REG_PX; i += 1024) {
        int rx = i % RS;
        int ry = i / RS;
        int xx = ox + rx;
        int yy = oy + ry;
        if (xx < 0 || xx >= NW || yy < 0 || yy >= NH) continue;
        float v3 = reg[i * 4 + 3];
        if (v3 == 0.0f) continue;   // exact: img in [0,1] => c_i <= w => all zero
        int o = yy * NW + xx;
        float* p = a3 + (size_t)o * 3;
        atomicAdd(p + 0, reg[i * 4 + 0]);
        atomicAdd(p + 1, reg[i * 4 + 1]);
        atomicAdd(p + 2, reg[i * 4 + 2]);
        atomicAdd(wv + o, v3);
    }
}

// Fused: erode (min, +inf pad) -> dilate (max, -inf pad) of both occupancy masks
// + final blend + output store. LDS-staged separately for both directions.
// Staged path covers p<=8 (k<=17); brute-force global path beyond.
__global__ __launch_bounds__(256) void morph_compose_kernel(
        const float* __restrict__ acc3_0, const float* __restrict__ acc3_1,
        const float* __restrict__ w0p, const float* __restrict__ w1p,
        float* __restrict__ out, const int* __restrict__ kptr) {
    __shared__ float occA[64 * 64], occB[64 * 64];
    __shared__ float erA[48 * 48], erB[48 * 48];

    const int t = threadIdx.x;
    const int b = blockIdx.z;
    const int x0 = blockIdx.x * 32;
    const int y0 = blockIdx.y * 32;
    const int k = *kptr;
    const int p = k >> 1;

    const float* wa = w0p + (size_t)b * NHW;
    const float* wb = w1p + (size_t)b * NHW;

    float mA[4], mB[4];

    if (p <= 8) {
        const int OS = 32 + 4 * p;
        const int ES = 32 + 2 * p;
        for (int i = t; i < OS * OS; i += 256) {
            int sx = x0 - 2 * p + (i % OS);
            int sy = y0 - 2 * p + (i / OS);
            float oa = 1.0f, ob = 1.0f;   // +inf pad for erode == treat OOB as occupied
            if (sx >= 0 && sx < NW && sy >= 0 && sy < NH) {
                oa = (wa[sy * NW + sx] != 0.0f) ? 1.0f : 0.0f;
                ob = (wb[sy * NW + sx] != 0.0f) ? 1.0f : 0.0f;
            }
            occA[i] = oa; occB[i] = ob;
        }
        __syncthreads();
        for (int i = t; i < ES * ES; i += 256) {
            int lx = i % ES, ly = i / ES;
            int ex = x0 - p + lx, ey = y0 - p + ly;
            float ea = 0.0f, eb = 0.0f;   // -inf pad for dilate == 0 (er in {0,1})
            if (ex >= 0 && ex < NW && ey >= 0 && ey < NH) {
                ea = 1.0f; eb = 1.0f;
                for (int dy = -p; dy <= p; ++dy)
                    for (int dx = -p; dx <= p; ++dx) {
                        int oi = (ly + p + dy) * OS + (lx + p + dx);
                        ea = fminf(ea, occA[oi]);
                        eb = fminf(eb, occB[oi]);
                    }
            }
            erA[i] = ea; erB[i] = eb;
        }
        __syncthreads();
#pragma unroll
        for (int r = 0; r < 4; ++r) {
            int lx = t & 31, ly = (t >> 5) + r * 8;
            float ma = 0.0f, mb = 0.0f;
            for (int dy = -p; dy <= p; ++dy)
                for (int dx = -p; dx <= p; ++dx) {
                    int ei = (ly + p + dy) * ES + (lx + p + dx);
                    ma = fmaxf(ma, erA[ei]);
                    mb = fmaxf(mb, erB[ei]);
                }
            mA[r] = ma; mB[r] = mb;
        }
    } else {
        // brute-force fallback, never taken for k<=17; correctness insurance
#pragma unroll
        for (int r = 0; r < 4; ++r) {
            int x = x0 + (t & 31), y = y0 + (t >> 5) + r * 8;
            float ma = 0.0f, mb = 0.0f;
            for (int dy2 = -p; dy2 <= p; ++dy2) {
                int qy = y + dy2; if (qy < 0 || qy >= NH) continue;
                for (int dx2 = -p; dx2 <= p; ++dx2) {
                    int qx = x + dx2; if (qx < 0 || qx >= NW) continue;
                    if (ma >= 1.0f && mb >= 1.0f) break;
                    float ea = 1.0f, eb = 1.0f;
                    for (int dy = -p; dy <= p; ++dy) {
                        int yy = qy + dy; if (yy < 0 || yy >= NH) continue;
                        for (int dx = -p; dx <= p; ++dx) {
                            int xx = qx + dx; if (xx < 0 || xx >= NW) continue;
                            if (wa[yy * NW + xx] == 0.0f) ea = 0.0f;
                            if (wb[yy * NW + xx] == 0.0f) eb = 0.0f;
                        }
                    }
                    ma = fmaxf(ma, ea);
                    mb = fmaxf(mb, eb);
                }
            }
            mA[r] = ma; mB[r] = mb;
        }
    }

    const float* a0 = acc3_0 + (size_t)b * NHW * 3;
    const float* a1 = acc3_1 + (size_t)b * NHW * 3;
    float* o0 = out + (size_t)b * 4 * NHW;
    float* o1 = out + (size_t)NB * 4 * NHW + (size_t)b * 4 * NHW;

#pragma unroll
    for (int r = 0; r < 4; ++r) {
        int lx = t & 31, ly = (t >> 5) + r * 8;
        int x = x0 + lx, y = y0 + ly;
        int hw = y * NW + x;
        float n0 = wa[hw];
        float n1 = wb[hw];
        float d0 = (n0 == 0.0f) ? 1.0f : n0;
        float d1 = (n1 == 0.0f) ? 1.0f : n1;
        const float* c0p = a0 + (size_t)hw * 3;
        const float* c1p = a1 + (size_t)hw * 3;
        float m0 = mA[r], m1 = mB[r];
#pragma unroll
        for (int c = 0; c < 3; ++c) {
            float w0c = c0p[c] / d0;
            float w1c = c1p[c] / d1;
            o0[c * NHW + hw] = m0 * w0c + (1.0f - m0) * w1c;
            o1[c * NHW + hw] = m1 * w1c + (1.0f - m1) * w0c;
        }
        o0[3 * NHW + hw] = m0;
        o1[3 * NHW + hw] = m1;
    }
}

extern "C" void kernel_launch(void* const* d_in, const int* in_sizes, int n_in,
                              void* d_out, int out_size, void* d_ws, size_t ws_size,
                              hipStream_t stream) {
    const float* I0  = (const float*)d_in[0];
    const float* I1  = (const float*)d_in[1];
    const float* f01 = (const float*)d_in[2];
    const float* f10 = (const float*)d_in[3];
    const int*  kptr = (const int*)d_in[4];

    float* ws = (float*)d_ws;
    const size_t n = (size_t)NB * NHW;
    float* lab0   = ws;            // 3n (interleaved)
    float* lab1   = lab0 + 3 * n;  // 3n (interleaved)
    float* acc3_0 = lab1 + 3 * n;  // 3n (interleaved)
    float* acc3_1 = acc3_0 + 3 * n;// 3n (interleaved)
    float* w0     = acc3_1 + 3 * n;// n (planar)
    float* w1     = w0 + n;        // n (planar)

    // zero acc3_0, acc3_1, w0, w1 (contiguous 8n floats)
    hipMemsetAsync(acc3_0, 0, 8 * n * sizeof(float), stream);

    const int T = 256;
    int gLab = (2 * NB * NHW + T - 1) / T;
    dim3 gTile(NW / TS, NH / TS, NB);
    dim3 gCmp(NW / 32, NH / 32, NB);

    lab_kernel<<<gLab, T, 0, stream>>>(I0, I1, lab0, lab1);
    splat_tile_kernel<<<gTile, 1024, 0, stream>>>(I0, lab0, lab1, f01, acc3_0, w0);
    splat_tile_kernel<<<gTile, 1024, 0, stream>>>(I1, lab1, lab0, f10, acc3_1, w1);
    morph_compose_kernel<<<gCmp, T, 0, stream>>>(acc3_0, acc3_1, w0, w1, (float*)d_out, kptr);
}

// Round 6
// 1230.389 us; speedup vs baseline: 1.0379x; 1.0379x over previous
//
#include <hip/hip_runtime.h>

#define NB 4
#define NH 1024
#define NW 1024
#define NHW (NH * NW)

#define TS 32          // source tile side
#define HP 16          // halo
#define RS 64          // region side = TS + 2*HP
#define REG_PX (RS * RS)

__device__ __forceinline__ float srgb2lin(float v) {
    return v > 0.04045f ? powf((v + 0.055f) * (1.0f / 1.055f), 2.4f) : v * (1.0f / 12.92f);
}

__device__ __forceinline__ float labf(float t) {
    return t > 0.008856f ? cbrtf(t) : 7.787f * t + 4.0f / 29.0f;
}

// Compute Lab for both images, INTERLEAVED (hw,3) output for gather locality.
__global__ void lab_kernel(const float* __restrict__ I0, const float* __restrict__ I1,
                           float* __restrict__ lab0, float* __restrict__ lab1) {
    int idx = blockIdx.x * blockDim.x + threadIdx.x;
    const int total = 2 * NB * NHW;
    if (idx >= total) return;
    int img = (idx >= NB * NHW) ? 1 : 0;
    int p = idx - img * NB * NHW;
    int b = p / NHW;
    int hw = p - b * NHW;
    const float* src = (img ? I1 : I0) + (size_t)b * 3 * NHW + hw;
    float* dst = (img ? lab1 : lab0) + ((size_t)b * NHW + hw) * 3;

    float r = srgb2lin(src[0]);
    float g = srgb2lin(src[NHW]);
    float bl = srgb2lin(src[2 * NHW]);

    float X = (0.412453f * r + 0.35758f * g + 0.180423f * bl) * (1.0f / 0.95047f);
    float Y = (0.212671f * r + 0.71516f * g + 0.072169f * bl);
    float Z = (0.019334f * r + 0.119193f * g + 0.950227f * bl) * (1.0f / 1.08883f);

    float fx = labf(X);
    float fy = labf(Y);
    float fz = labf(Z);

    dst[0] = 116.0f * fy - 16.0f;
    dst[1] = 500.0f * (fx - fy);
    dst[2] = 200.0f * (fy - fz);
}

// Fused z-metric + forward splat, LDS-privatized per 32x32 source tile.
// LDS region is PLANAR [4][RS*RS]: ds-atomic bank = rx%32 -> all 32 banks
// (interleaved [RS*RS][4] layout used only 8 banks -> ~8-way conflicts,
// which was the measured bottleneck across rounds 2-4).
// 1024 threads, 1 px/thread; 64 KB LDS => 2 blocks/CU = 32 waves/CU.
__global__ __launch_bounds__(1024, 8) void splat_tile_kernel(
        const float* __restrict__ img,
        const float* __restrict__ lab_a,   // interleaved 3
        const float* __restrict__ lab_b,   // interleaved 3
        const float* __restrict__ flow,
        float* __restrict__ acc3,
        float* __restrict__ wacc) {
    __shared__ float reg[4 * REG_PX];   // 64 KB, planar: plane c at reg + c*REG_PX

    const int t = threadIdx.x;
    const int b = blockIdx.z;
    const int tile_x0 = blockIdx.x * TS;
    const int tile_y0 = blockIdx.y * TS;
    const int ox = tile_x0 - HP;
    const int oy = tile_y0 - HP;

    {
        float4* r4 = (float4*)reg;
        const float4 z4 = make_float4(0.f, 0.f, 0.f, 0.f);
        for (int i = t; i < REG_PX; i += 1024) r4[i] = z4;
    }
    __syncthreads();

    const int tx = t & 31;
    const int ty = t >> 5;   // 0..31

    const float* fb = flow  + (size_t)b * 2 * NHW;
    const float* ib = img   + (size_t)b * 3 * NHW;
    const float* la = lab_a + (size_t)b * NHW * 3;
    const float* lb = lab_b + (size_t)b * NHW * 3;
    float* a3 = acc3 + (size_t)b * NHW * 3;
    float* wv = wacc + (size_t)b * NHW;

    const int y = tile_y0 + ty;
    const int x = tile_x0 + tx;
    const int hw = y * NW + x;

    const float fy_d = fb[hw];         // flow channel 0 = y displacement
    const float fx_d = fb[NHW + hw];   // flow channel 1 = x displacement

    // ---- backward warp gather (grid_sample_border convention) ----
    float base_y = -1.0f + 2.0f * (float)y / (float)(NH - 1);
    float base_x = -1.0f + 2.0f * (float)x / (float)(NW - 1);
    float gy = 2.0f * fy_d / (float)NH + base_y;
    float gx = 2.0f * fx_d / (float)NW + base_x;
    float ys = fminf(fmaxf(((gy + 1.0f) * (float)NH - 1.0f) * 0.5f, 0.0f), (float)(NH - 1));
    float xs = fminf(fmaxf(((gx + 1.0f) * (float)NW - 1.0f) * 0.5f, 0.0f), (float)(NW - 1));
    float y0f = floorf(ys), x0f = floorf(xs);
    int y0 = (int)y0f, x0 = (int)x0f;
    int y1 = min(y0 + 1, NH - 1), x1 = min(x0 + 1, NW - 1);
    float wy = ys - y0f, wx = xs - x0f;

    const float* p00 = lb + (size_t)(y0 * NW + x0) * 3;
    const float* p01 = lb + (size_t)(y0 * NW + x1) * 3;
    const float* p10 = lb + (size_t)(y1 * NW + x0) * 3;
    const float* p11 = lb + (size_t)(y1 * NW + x1) * 3;
    const float* pa  = la + (size_t)hw * 3;

    float ss = 0.0f;
#pragma unroll
    for (int c = 0; c < 3; ++c) {
        float top = p00[c] * (1.0f - wx) + p01[c] * wx;
        float bot = p10[c] * (1.0f - wx) + p11[c] * wx;
        float v = top * (1.0f - wy) + bot * wy;
        float d = pa[c] - v;
        ss += d * d;
    }
    float w = expf(-0.1f * sqrtf(ss));

    // ---- forward splat ----
    float sx = fx_d + (float)x;
    float sy = fy_d + (float)y;
    int ix0 = (int)floorf(sx);
    int iy0 = (int)floorf(sy);

    float c0 = ib[hw] * w;
    float c1 = ib[NHW + hw] * w;
    float c2 = ib[2 * NHW + hw] * w;

#pragma unroll
    for (int dy = 0; dy < 2; ++dy) {
        int yi = iy0 + dy;
        if (yi < 0 || yi >= NH) continue;
        float wgy = 1.0f - fabsf(sy - (float)yi);
#pragma unroll
        for (int dx = 0; dx < 2; ++dx) {
            int xi = ix0 + dx;
            if (xi < 0 || xi >= NW) continue;
            float wg = wgy * (1.0f - fabsf(sx - (float)xi));
            int rx = xi - ox;
            int ry = yi - oy;
            if (rx >= 0 && rx < RS && ry >= 0 && ry < RS) {
                int cell = (ry << 6) + rx;
                atomicAdd(reg + cell,              c0 * wg);
                atomicAdd(reg + REG_PX + cell,     c1 * wg);
                atomicAdd(reg + 2 * REG_PX + cell, c2 * wg);
                atomicAdd(reg + 3 * REG_PX + cell, w * wg);
            } else {
                int o = yi * NW + xi;
                float* p = a3 + (size_t)o * 3;
                atomicAdd(p + 0, c0 * wg);
                atomicAdd(p + 1, c1 * wg);
                atomicAdd(p + 2, c2 * wg);
                atomicAdd(wv + o, w * wg);
            }
        }
    }
    __syncthreads();

    // ---- flush LDS region to global (coalesced, aggregated, zero-skipped) ----
    for (int i = t; i < REG_PX; i += 1024) {
        int rx = i & (RS - 1);
        int ry = i >> 6;
        int xx = ox + rx;
        int yy = oy + ry;
        if (xx < 0 || xx >= NW || yy < 0 || yy >= NH) continue;
        float v3 = reg[3 * REG_PX + i];
        if (v3 == 0.0f) continue;   // exact: img in [0,1] => c_i <= w => all zero
        int o = yy * NW + xx;
        float* p = a3 + (size_t)o * 3;
        atomicAdd(p + 0, reg[i]);
        atomicAdd(p + 1, reg[REG_PX + i]);
        atomicAdd(p + 2, reg[2 * REG_PX + i]);
        atomicAdd(wv + o, v3);
    }
}

// Fused: erode (min, +inf pad) -> dilate (max, -inf pad) of both occupancy masks
// + final blend + output store. LDS-staged separately for both directions.
// Staged path covers p<=8 (k<=17); brute-force global path beyond.
__global__ __launch_bounds__(256) void morph_compose_kernel(
        const float* __restrict__ acc3_0, const float* __restrict__ acc3_1,
        const float* __restrict__ w0p, const float* __restrict__ w1p,
        float* __restrict__ out, const int* __restrict__ kptr) {
    __shared__ float occA[64 * 64], occB[64 * 64];
    __shared__ float erA[48 * 48], erB[48 * 48];

    const int t = threadIdx.x;
    const int b = blockIdx.z;
    const int x0 = blockIdx.x * 32;
    const int y0 = blockIdx.y * 32;
    const int k = *kptr;
    const int p = k >> 1;

    const float* wa = w0p + (size_t)b * NHW;
    const float* wb = w1p + (size_t)b * NHW;

    float mA[4], mB[4];

    if (p <= 8) {
        const int OS = 32 + 4 * p;
        const int ES = 32 + 2 * p;
        for (int i = t; i < OS * OS; i += 256) {
            int sx = x0 - 2 * p + (i % OS);
            int sy = y0 - 2 * p + (i / OS);
            float oa = 1.0f, ob = 1.0f;   // +inf pad for erode == treat OOB as occupied
            if (sx >= 0 && sx < NW && sy >= 0 && sy < NH) {
                oa = (wa[sy * NW + sx] != 0.0f) ? 1.0f : 0.0f;
                ob = (wb[sy * NW + sx] != 0.0f) ? 1.0f : 0.0f;
            }
            occA[i] = oa; occB[i] = ob;
        }
        __syncthreads();
        for (int i = t; i < ES * ES; i += 256) {
            int lx = i % ES, ly = i / ES;
            int ex = x0 - p + lx, ey = y0 - p + ly;
            float ea = 0.0f, eb = 0.0f;   // -inf pad for dilate == 0 (er in {0,1})
            if (ex >= 0 && ex < NW && ey >= 0 && ey < NH) {
                ea = 1.0f; eb = 1.0f;
                for (int dy = -p; dy <= p; ++dy)
                    for (int dx = -p; dx <= p; ++dx) {
                        int oi = (ly + p + dy) * OS + (lx + p + dx);
                        ea = fminf(ea, occA[oi]);
                        eb = fminf(eb, occB[oi]);
                    }
            }
            erA[i] = ea; erB[i] = eb;
        }
        __syncthreads();
#pragma unroll
        for (int r = 0; r < 4; ++r) {
            int lx = t & 31, ly = (t >> 5) + r * 8;
            float ma = 0.0f, mb = 0.0f;
            for (int dy = -p; dy <= p; ++dy)
                for (int dx = -p; dx <= p; ++dx) {
                    int ei = (ly + p + dy) * ES + (lx + p + dx);
                    ma = fmaxf(ma, erA[ei]);
                    mb = fmaxf(mb, erB[ei]);
                }
            mA[r] = ma; mB[r] = mb;
        }
    } else {
        // brute-force fallback, never taken for k<=17; correctness insurance
#pragma unroll
        for (int r = 0; r < 4; ++r) {
            int x = x0 + (t & 31), y = y0 + (t >> 5) + r * 8;
            float ma = 0.0f, mb = 0.0f;
            for (int dy2 = -p; dy2 <= p; ++dy2) {
                int qy = y + dy2; if (qy < 0 || qy >= NH) continue;
                for (int dx2 = -p; dx2 <= p; ++dx2) {
                    int qx = x + dx2; if (qx < 0 || qx >= NW) continue;
                    if (ma >= 1.0f && mb >= 1.0f) break;
                    float ea = 1.0f, eb = 1.0f;
                    for (int dy = -p; dy <= p; ++dy) {
                        int yy = qy + dy; if (yy < 0 || yy >= NH) continue;
                        for (int dx = -p; dx <= p; ++dx) {
                            int xx = qx + dx; if (xx < 0 || xx >= NW) continue;
                            if (wa[yy * NW + xx] == 0.0f) ea = 0.0f;
                            if (wb[yy * NW + xx] == 0.0f) eb = 0.0f;
                        }
                    }
                    ma = fmaxf(ma, ea);
                    mb = fmaxf(mb, eb);
                }
            }
            mA[r] = ma; mB[r] = mb;
        }
    }

    const float* a0 = acc3_0 + (size_t)b * NHW * 3;
    const float* a1 = acc3_1 + (size_t)b * NHW * 3;
    float* o0 = out + (size_t)b * 4 * NHW;
    float* o1 = out + (size_t)NB * 4 * NHW + (size_t)b * 4 * NHW;

#pragma unroll
    for (int r = 0; r < 4; ++r) {
        int lx = t & 31, ly = (t >> 5) + r * 8;
        int x = x0 + lx, y = y0 + ly;
        int hw = y * NW + x;
        float n0 = wa[hw];
        float n1 = wb[hw];
        float d0 = (n0 == 0.0f) ? 1.0f : n0;
        float d1 = (n1 == 0.0f) ? 1.0f : n1;
        const float* c0p = a0 + (size_t)hw * 3;
        const float* c1p = a1 + (size_t)hw * 3;
        float m0 = mA[r], m1 = mB[r];
#pragma unroll
        for (int c = 0; c < 3; ++c) {
            float w0c = c0p[c] / d0;
            float w1c = c1p[c] / d1;
            o0[c * NHW + hw] = m0 * w0c + (1.0f - m0) * w1c;
            o1[c * NHW + hw] = m1 * w1c + (1.0f - m1) * w0c;
        }
        o0[3 * NHW + hw] = m0;
        o1[3 * NHW + hw] = m1;
    }
}

extern "C" void kernel_launch(void* const* d_in, const int* in_sizes, int n_in,
                              void* d_out, int out_size, void* d_ws, size_t ws_size,
                              hipStream_t stream) {
    const float* I0  = (const float*)d_in[0];
    const float* I1  = (const float*)d_in[1];
    const float* f01 = (const float*)d_in[2];
    const float* f10 = (const float*)d_in[3];
    const int*  kptr = (const int*)d_in[4];

    float* ws = (float*)d_ws;
    const size_t n = (size_t)NB * NHW;
    float* lab0   = ws;            // 3n (interleaved)
    float* lab1   = lab0 + 3 * n;  // 3n (interleaved)
    float* acc3_0 = lab1 + 3 * n;  // 3n (interleaved)
    float* acc3_1 = acc3_0 + 3 * n;// 3n (interleaved)
    float* w0     = acc3_1 + 3 * n;// n (planar)
    float* w1     = w0 + n;        // n (planar)

    // zero acc3_0, acc3_1, w0, w1 (contiguous 8n floats)
    hipMemsetAsync(acc3_0, 0, 8 * n * sizeof(float), stream);

    const int T = 256;
    int gLab = (2 * NB * NHW + T - 1) / T;
    dim3 gTile(NW / TS, NH / TS, NB);
    dim3 gCmp(NW / 32, NH / 32, NB);

    lab_kernel<<<gLab, T, 0, stream>>>(I0, I1, lab0, lab1);
    splat_tile_kernel<<<gTile, 1024, 0, stream>>>(I0, lab0, lab1, f01, acc3_0, w0);
    splat_tile_kernel<<<gTile, 1024, 0, stream>>>(I1, lab1, lab0, f10, acc3_1, w1);
    morph_compose_kernel<<<gCmp, T, 0, stream>>>(acc3_0, acc3_1, w0, w1, (float*)d_out, kptr);
}

// Round 7
// 1064.779 us; speedup vs baseline: 1.1993x; 1.1555x over previous
//
#include <hip/hip_runtime.h>

#define NB 4
#define NH 1024
#define NW 1024
#define NHW (NH * NW)

#define TS 32          // owned output tile side
#define HP 16          // halo: source px within +-HP of tile contribute via LDS
#define SRCS 64        // source region side = TS + 2*HP
#define SRC_PX (SRCS * SRCS)
#define TILE_PX (TS * TS)

__device__ __forceinline__ float srgb2lin(float v) {
    return v > 0.04045f ? powf((v + 0.055f) * (1.0f / 1.055f), 2.4f) : v * (1.0f / 12.92f);
}

__device__ __forceinline__ float labf(float t) {
    return t > 0.008856f ? cbrtf(t) : 7.787f * t + 4.0f / 29.0f;
}

// Compute Lab for both images, INTERLEAVED (hw,3) output for gather locality.
__global__ void lab_kernel(const float* __restrict__ I0, const float* __restrict__ I1,
                           float* __restrict__ lab0, float* __restrict__ lab1) {
    int idx = blockIdx.x * blockDim.x + threadIdx.x;
    const int total = 2 * NB * NHW;
    if (idx >= total) return;
    int img = (idx >= NB * NHW) ? 1 : 0;
    int p = idx - img * NB * NHW;
    int b = p / NHW;
    int hw = p - b * NHW;
    const float* src = (img ? I1 : I0) + (size_t)b * 3 * NHW + hw;
    float* dst = (img ? lab1 : lab0) + ((size_t)b * NHW + hw) * 3;

    float r = srgb2lin(src[0]);
    float g = srgb2lin(src[NHW]);
    float bl = srgb2lin(src[2 * NHW]);

    float X = (0.412453f * r + 0.35758f * g + 0.180423f * bl) * (1.0f / 0.95047f);
    float Y = (0.212671f * r + 0.71516f * g + 0.072169f * bl);
    float Z = (0.019334f * r + 0.119193f * g + 0.950227f * bl) * (1.0f / 1.08883f);

    float fx = labf(X);
    float fy = labf(Y);
    float fz = labf(Z);

    dst[0] = 116.0f * fy - 16.0f;
    dst[1] = 500.0f * (fx - fy);
    dst[2] = 200.0f * (fy - fz);
}

// z-metric + exp, one float per pixel. Isolates the scattered bilinear gather.
// block = 32x8 px patch for 2D gather locality.
__global__ __launch_bounds__(256) void wmap_kernel(
        const float* __restrict__ lab_a,   // interleaved 3
        const float* __restrict__ lab_b,   // interleaved 3
        const float* __restrict__ flow,
        float* __restrict__ wm) {
    const int tx = threadIdx.x & 31;
    const int ty = threadIdx.x >> 5;
    const int x = blockIdx.x * 32 + tx;
    const int y = blockIdx.y * 8 + ty;
    const int b = blockIdx.z;
    const int hw = y * NW + x;

    const float* fb = flow + (size_t)b * 2 * NHW;
    const float fy_d = fb[hw];
    const float fx_d = fb[NHW + hw];

    float base_y = -1.0f + 2.0f * (float)y / (float)(NH - 1);
    float base_x = -1.0f + 2.0f * (float)x / (float)(NW - 1);
    float gy = 2.0f * fy_d / (float)NH + base_y;
    float gx = 2.0f * fx_d / (float)NW + base_x;
    float ys = fminf(fmaxf(((gy + 1.0f) * (float)NH - 1.0f) * 0.5f, 0.0f), (float)(NH - 1));
    float xs = fminf(fmaxf(((gx + 1.0f) * (float)NW - 1.0f) * 0.5f, 0.0f), (float)(NW - 1));
    float y0f = floorf(ys), x0f = floorf(xs);
    int y0 = (int)y0f, x0 = (int)x0f;
    int y1 = min(y0 + 1, NH - 1), x1 = min(x0 + 1, NW - 1);
    float wy = ys - y0f, wx = xs - x0f;

    const float* lb = lab_b + (size_t)b * NHW * 3;
    const float* p00 = lb + (size_t)(y0 * NW + x0) * 3;
    const float* p01 = lb + (size_t)(y0 * NW + x1) * 3;
    const float* p10 = lb + (size_t)(y1 * NW + x0) * 3;
    const float* p11 = lb + (size_t)(y1 * NW + x1) * 3;
    const float* pa  = lab_a + ((size_t)b * NHW + hw) * 3;

    float ss = 0.0f;
#pragma unroll
    for (int c = 0; c < 3; ++c) {
        float top = p00[c] * (1.0f - wx) + p01[c] * wx;
        float bot = p10[c] * (1.0f - wx) + p11[c] * wx;
        float v = top * (1.0f - wy) + bot * wy;
        float d = pa[c] - v;
        ss += d * d;
    }
    wm[(size_t)b * NHW + hw] = expf(-0.1f * sqrtf(ss));
}

// Ownership splat: block owns a 32x32 OUTPUT tile. Reads the 64x64 source
// region (coalesced), LDS-accumulates taps landing in its tile, then flushes
// with 4 coalesced global atomics per owned pixel (vs 16 scattered before).
// Taps displaced >HP from their source px are handled by the unique block
// whose tile contains the source px, via global-atomic fallback (~9% of px).
__global__ __launch_bounds__(1024, 2) void splat_own_kernel(
        const float* __restrict__ img,
        const float* __restrict__ wm,
        const float* __restrict__ flow,
        float* __restrict__ acc3,
        float* __restrict__ wacc) {
    __shared__ float acc[4][TILE_PX];   // 16 KB planar

    const int t = threadIdx.x;
    const int b = blockIdx.z;
    const int tx0 = blockIdx.x * TS;
    const int ty0 = blockIdx.y * TS;
    const int ox = tx0 - HP;
    const int oy = ty0 - HP;

    acc[0][t] = 0.0f; acc[1][t] = 0.0f; acc[2][t] = 0.0f; acc[3][t] = 0.0f;
    __syncthreads();

    const float* fb = flow + (size_t)b * 2 * NHW;
    const float* ib = img  + (size_t)b * 3 * NHW;
    const float* wb = wm   + (size_t)b * NHW;
    float* a3 = acc3 + (size_t)b * NHW * 3;
    float* wv = wacc + (size_t)b * NHW;

#pragma unroll
    for (int kk = 0; kk < 4; ++kk) {
        const int i = t + kk * 1024;
        const int rx = i & (SRCS - 1);
        const int ry = i >> 6;
        const int sx = ox + rx;
        const int sy = oy + ry;
        if (sx < 0 || sx >= NW || sy < 0 || sy >= NH) continue;
        const int hw = sy * NW + sx;

        const float fy_d = fb[hw];
        const float fx_d = fb[NHW + hw];
        const float w = wb[hw];

        const float c0 = ib[hw] * w;
        const float c1 = ib[NHW + hw] * w;
        const float c2 = ib[2 * NHW + hw] * w;

        const float px = fx_d + (float)sx;
        const float py = fy_d + (float)sy;
        const int ix0 = (int)floorf(px);
        const int iy0 = (int)floorf(py);

        const bool interior = (sx >= tx0) && (sx < tx0 + TS) && (sy >= ty0) && (sy < ty0 + TS);

#pragma unroll
        for (int dy = 0; dy < 2; ++dy) {
            const int yi = iy0 + dy;
            if (yi < 0 || yi >= NH) continue;
            const float wgy = 1.0f - fabsf(py - (float)yi);
#pragma unroll
            for (int dx = 0; dx < 2; ++dx) {
                const int xi = ix0 + dx;
                if (xi < 0 || xi >= NW) continue;
                const float wg = wgy * (1.0f - fabsf(px - (float)xi));
                const int lx = xi - tx0;
                const int ly = yi - ty0;
                if (lx >= 0 && lx < TS && ly >= 0 && ly < TS) {
                    const int cell = (ly << 5) + lx;
                    atomicAdd(&acc[0][cell], c0 * wg);
                    atomicAdd(&acc[1][cell], c1 * wg);
                    atomicAdd(&acc[2][cell], c2 * wg);
                    atomicAdd(&acc[3][cell], w * wg);
                } else if (interior) {
                    // Is this tap covered by the block owning the tap's tile?
                    const int ttx0 = xi & ~(TS - 1);
                    const int tty0 = yi & ~(TS - 1);
                    const bool covered = (sx >= ttx0 - HP) && (sx < ttx0 + TS + HP) &&
                                         (sy >= tty0 - HP) && (sy < tty0 + TS + HP);
                    if (!covered) {
                        const int o = yi * NW + xi;
                        float* p = a3 + (size_t)o * 3;
                        atomicAdd(p + 0, c0 * wg);
                        atomicAdd(p + 1, c1 * wg);
                        atomicAdd(p + 2, c2 * wg);
                        atomicAdd(wv + o, w * wg);
                    }
                }
            }
        }
    }
    __syncthreads();

    // ---- flush own tile: 4 coalesced global atomics per pixel ----
    {
        const int lx = t & (TS - 1);
        const int ly = t >> 5;
        const int o = (ty0 + ly) * NW + (tx0 + lx);
        const float v3 = acc[3][t];
        if (v3 != 0.0f) {
            float* p = a3 + (size_t)o * 3;
            atomicAdd(p + 0, acc[0][t]);
            atomicAdd(p + 1, acc[1][t]);
            atomicAdd(p + 2, acc[2][t]);
            atomicAdd(wv + o, v3);
        }
    }
}

// Fused: erode (min, +inf pad) -> dilate (max, -inf pad) of both occupancy masks
// + final blend + output store. LDS-staged separately for both directions.
// Staged path covers p<=8 (k<=17); brute-force global path beyond.
__global__ __launch_bounds__(256) void morph_compose_kernel(
        const float* __restrict__ acc3_0, const float* __restrict__ acc3_1,
        const float* __restrict__ w0p, const float* __restrict__ w1p,
        float* __restrict__ out, const int* __restrict__ kptr) {
    __shared__ float occA[64 * 64], occB[64 * 64];
    __shared__ float erA[48 * 48], erB[48 * 48];

    const int t = threadIdx.x;
    const int b = blockIdx.z;
    const int x0 = blockIdx.x * 32;
    const int y0 = blockIdx.y * 32;
    const int k = *kptr;
    const int p = k >> 1;

    const float* wa = w0p + (size_t)b * NHW;
    const float* wb = w1p + (size_t)b * NHW;

    float mA[4], mB[4];

    if (p <= 8) {
        const int OS = 32 + 4 * p;
        const int ES = 32 + 2 * p;
        for (int i = t; i < OS * OS; i += 256) {
            int sx = x0 - 2 * p + (i % OS);
            int sy = y0 - 2 * p + (i / OS);
            float oa = 1.0f, ob = 1.0f;   // +inf pad for erode == treat OOB as occupied
            if (sx >= 0 && sx < NW && sy >= 0 && sy < NH) {
                oa = (wa[sy * NW + sx] != 0.0f) ? 1.0f : 0.0f;
                ob = (wb[sy * NW + sx] != 0.0f) ? 1.0f : 0.0f;
            }
            occA[i] = oa; occB[i] = ob;
        }
        __syncthreads();
        for (int i = t; i < ES * ES; i += 256) {
            int lx = i % ES, ly = i / ES;
            int ex = x0 - p + lx, ey = y0 - p + ly;
            float ea = 0.0f, eb = 0.0f;   // -inf pad for dilate == 0 (er in {0,1})
            if (ex >= 0 && ex < NW && ey >= 0 && ey < NH) {
                ea = 1.0f; eb = 1.0f;
                for (int dy = -p; dy <= p; ++dy)
                    for (int dx = -p; dx <= p; ++dx) {
                        int oi = (ly + p + dy) * OS + (lx + p + dx);
                        ea = fminf(ea, occA[oi]);
                        eb = fminf(eb, occB[oi]);
                    }
            }
            erA[i] = ea; erB[i] = eb;
        }
        __syncthreads();
#pragma unroll
        for (int r = 0; r < 4; ++r) {
            int lx = t & 31, ly = (t >> 5) + r * 8;
            float ma = 0.0f, mb = 0.0f;
            for (int dy = -p; dy <= p; ++dy)
                for (int dx = -p; dx <= p; ++dx) {
                    int ei = (ly + p + dy) * ES + (lx + p + dx);
                    ma = fmaxf(ma, erA[ei]);
                    mb = fmaxf(mb, erB[ei]);
                }
            mA[r] = ma; mB[r] = mb;
        }
    } else {
        // brute-force fallback, never taken for k<=17; correctness insurance
#pragma unroll
        for (int r = 0; r < 4; ++r) {
            int x = x0 + (t & 31), y = y0 + (t >> 5) + r * 8;
            float ma = 0.0f, mb = 0.0f;
            for (int dy2 = -p; dy2 <= p; ++dy2) {
                int qy = y + dy2; if (qy < 0 || qy >= NH) continue;
                for (int dx2 = -p; dx2 <= p; ++dx2) {
                    int qx = x + dx2; if (qx < 0 || qx >= NW) continue;
                    if (ma >= 1.0f && mb >= 1.0f) break;
                    float ea = 1.0f, eb = 1.0f;
                    for (int dy = -p; dy <= p; ++dy) {
                        int yy = qy + dy; if (yy < 0 || yy >= NH) continue;
                        for (int dx = -p; dx <= p; ++dx) {
                            int xx = qx + dx; if (xx < 0 || xx >= NW) continue;
                            if (wa[yy * NW + xx] == 0.0f) ea = 0.0f;
                            if (wb[yy * NW + xx] == 0.0f) eb = 0.0f;
                        }
                    }
                    ma = fmaxf(ma, ea);
                    mb = fmaxf(mb, eb);
                }
            }
            mA[r] = ma; mB[r] = mb;
        }
    }

    const float* a0 = acc3_0 + (size_t)b * NHW * 3;
    const float* a1 = acc3_1 + (size_t)b * NHW * 3;
    float* o0 = out + (size_t)b * 4 * NHW;
    float* o1 = out + (size_t)NB * 4 * NHW + (size_t)b * 4 * NHW;

#pragma unroll
    for (int r = 0; r < 4; ++r) {
        int lx = t & 31, ly = (t >> 5) + r * 8;
        int x = x0 + lx, y = y0 + ly;
        int hw = y * NW + x;
        float n0 = wa[hw];
        float n1 = wb[hw];
        float d0 = (n0 == 0.0f) ? 1.0f : n0;
        float d1 = (n1 == 0.0f) ? 1.0f : n1;
        const float* c0p = a0 + (size_t)hw * 3;
        const float* c1p = a1 + (size_t)hw * 3;
        float m0 = mA[r], m1 = mB[r];
#pragma unroll
        for (int c = 0; c < 3; ++c) {
            float w0c = c0p[c] / d0;
            float w1c = c1p[c] / d1;
            o0[c * NHW + hw] = m0 * w0c + (1.0f - m0) * w1c;
            o1[c * NHW + hw] = m1 * w1c + (1.0f - m1) * w0c;
        }
        o0[3 * NHW + hw] = m0;
        o1[3 * NHW + hw] = m1;
    }
}

extern "C" void kernel_launch(void* const* d_in, const int* in_sizes, int n_in,
                              void* d_out, int out_size, void* d_ws, size_t ws_size,
                              hipStream_t stream) {
    const float* I0  = (const float*)d_in[0];
    const float* I1  = (const float*)d_in[1];
    const float* f01 = (const float*)d_in[2];
    const float* f10 = (const float*)d_in[3];
    const int*  kptr = (const int*)d_in[4];

    float* ws = (float*)d_ws;
    const size_t n = (size_t)NB * NHW;
    // Layout (12n floats total). lab is DEAD after the wmap kernels, so
    // acc3_1/w1 overlay it; the overlaying memset runs after wmaps.
    float* lab0   = ws;            // [0, 3n)
    float* lab1   = ws + 3 * n;    // [3n, 6n)
    float* wm0    = ws + 6 * n;    // [6n, 7n)
    float* wm1    = ws + 7 * n;    // [7n, 8n)
    float* acc3_0 = ws + 8 * n;    // [8n, 11n)
    float* w0     = ws + 11 * n;   // [11n, 12n)
    float* acc3_1 = ws;            // [0, 3n)  overlays lab0
    float* w1     = ws + 3 * n;    // [3n, 4n) overlays lab1 head

    const int T = 256;
    int gLab = (2 * NB * NHW + T - 1) / T;
    dim3 gW(NW / 32, NH / 8, NB);
    dim3 gTile(NW / TS, NH / TS, NB);
    dim3 gCmp(NW / 32, NH / 32, NB);

    lab_kernel<<<gLab, T, 0, stream>>>(I0, I1, lab0, lab1);
    wmap_kernel<<<gW, T, 0, stream>>>(lab0, lab1, f01, wm0);
    wmap_kernel<<<gW, T, 0, stream>>>(lab1, lab0, f10, wm1);
    hipMemsetAsync(acc3_0, 0, 4 * n * sizeof(float), stream);   // acc3_0 + w0
    hipMemsetAsync(acc3_1, 0, 4 * n * sizeof(float), stream);   // acc3_1 + w1 (over dead lab)
    splat_own_kernel<<<gTile, 1024, 0, stream>>>(I0, wm0, f01, acc3_0, w0);
    splat_own_kernel<<<gTile, 1024, 0, stream>>>(I1, wm1, f10, acc3_1, w1);
    morph_compose_kernel<<<gCmp, T, 0, stream>>>(acc3_0, acc3_1, w0, w1, (float*)d_out, kptr);
}